// Round 3
// baseline (1169.157 us; speedup 1.0000x reference)
//
#include <hip/hip_runtime.h>
#include <math.h>

#define N_PTS 8192
#define BATCH 2
#define KNB 16
#define NQ (BATCH * N_PTS)          // 16384
#define FLT_BIG 3.4e38f

// spatial grid
#define LBOX 5.25f
#define H    0.25f
#define INVH 4.0f
#define NC   42
#define NCELL (NC * NC * NC)        // 74088
#define MCELL (2 * NCELL)           // 148176 (both batches)

__device__ __forceinline__ float med3f(float a, float b, float c) {
#if __has_builtin(__builtin_amdgcn_fmed3f)
    return __builtin_amdgcn_fmed3f(a, b, c);
#else
    return fmaxf(fminf(a, b), fminf(fmaxf(a, b), c));
#endif
}
__device__ __forceinline__ int med3i(int a, int b, int c) {
    return max(min(a, b), min(max(a, b), c));
}

// ---------------- zero counts ----------------
__global__ __launch_bounds__(256) void kzero(int* __restrict__ p, int n) {
    const int i = blockIdx.x * 256 + threadIdx.x;
    if (i < n) p[i] = 0;
}

// ---------------- count points per cell ----------------
__global__ __launch_bounds__(256) void kcount(const float* __restrict__ pos,
                                              int* __restrict__ cnt,
                                              int* __restrict__ cellid) {
    const int g = blockIdx.x * 256 + threadIdx.x;      // global point id
    const int b = g >> 13;
    const float x = pos[g * 3 + 0], y = pos[g * 3 + 1], z = pos[g * 3 + 2];
    int cx = (int)floorf((x + LBOX) * INVH); cx = min(max(cx, 0), NC - 1);
    int cy = (int)floorf((y + LBOX) * INVH); cy = min(max(cy, 0), NC - 1);
    int cz = (int)floorf((z + LBOX) * INVH); cz = min(max(cz, 0), NC - 1);
    const int c = (((b * NC) + cz) * NC + cy) * NC + cx;
    cellid[g] = c;
    atomicAdd(&cnt[c], 1);
}

// ---------------- prefix sum, level 1: per-1024-block inclusive scan ----------------
__global__ __launch_bounds__(1024) void kscan1(const int* __restrict__ cnt,
                                               int* __restrict__ scanned,
                                               int* __restrict__ bsum) {
    __shared__ int sh[1024];
    const int t = threadIdx.x;
    const int idx = blockIdx.x * 1024 + t;
    int v = (idx < MCELL) ? cnt[idx] : 0;
    sh[t] = v;
    __syncthreads();
    for (int off = 1; off < 1024; off <<= 1) {
        const int add = (t >= off) ? sh[t - off] : 0;
        __syncthreads();
        sh[t] += add;
        __syncthreads();
    }
    if (idx < MCELL) scanned[idx] = sh[t];
    if (t == 1023) bsum[blockIdx.x] = sh[1023];
}

// ---------------- prefix sum, level 2: add block offsets -> cell_start ----------------
__global__ __launch_bounds__(1024) void kscan2(const int* __restrict__ scanned,
                                               const int* __restrict__ bsum,
                                               int* __restrict__ cell_start) {
    __shared__ int soff;
    const int t = threadIdx.x;
    const int blk = blockIdx.x;
    const int idx = blk * 1024 + t;
    if (t == 0) {
        int s = 0;
        for (int k = 0; k < blk; ++k) s += bsum[k];
        soff = s;
    }
    __syncthreads();
    if (idx < MCELL) cell_start[idx + 1] = scanned[idx] + soff;
    if (idx == 0) cell_start[0] = 0;
}

// ---------------- scatter points into sorted order ----------------
__global__ __launch_bounds__(256) void kscatter(const float* __restrict__ pos,
                                                const int* __restrict__ cellid,
                                                const int* __restrict__ cell_start,
                                                int* __restrict__ cnt2,
                                                float4* __restrict__ spp,
                                                int* __restrict__ sidx) {
    const int g = blockIdx.x * 256 + threadIdx.x;
    const int c = cellid[g];
    const int off = atomicAdd(&cnt2[c], 1);
    const int p = cell_start[c] + off;
    const float x = pos[g * 3 + 0], y = pos[g * 3 + 1], z = pos[g * 3 + 2];
    spp[p] = make_float4(-2.f * x, -2.f * y, -2.f * z, fmaf(x, x, fmaf(y, y, z * z)));
    sidx[p] = g & (N_PTS - 1);      // within-batch index
}

// ---------------- ring-search exact kNN ----------------
// thread = sorted slot (queries spatially coherent within a wave).
// key(p) = |p|^2 - 2 q.p  (monotone in true distance for fixed q).
__global__ __launch_bounds__(64) void ksearch(const float4* __restrict__ spp,
                                              const int* __restrict__ sidx,
                                              const int* __restrict__ cs,
                                              int* __restrict__ knn) {
    const int s = blockIdx.x * 64 + threadIdx.x;
    const int b = s >> 13;
    const float4 me = spp[s];
    const float qx = -0.5f * me.x, qy = -0.5f * me.y, qz = -0.5f * me.z;
    const float qsq = me.w;
    int cx = (int)floorf((qx + LBOX) * INVH); cx = min(max(cx, 0), NC - 1);
    int cy = (int)floorf((qy + LBOX) * INVH); cy = min(max(cy, 0), NC - 1);
    int cz = (int)floorf((qz + LBOX) * INVH); cz = min(max(cz, 0), NC - 1);

    // iterate exactly the cells with Chebyshev distance == R (grid-clipped)
    auto do_ring = [&](int R, auto&& body) {
        const int zlo = max(cz - R, 0), zhi = min(cz + R, NC - 1);
        const int ylo = max(cy - R, 0), yhi = min(cy + R, NC - 1);
        const int xlo = max(cx - R, 0), xhi = min(cx + R, NC - 1);
        for (int z = zlo; z <= zhi; ++z) {
            const bool zf = (z == cz - R) || (z == cz + R);
            for (int y = ylo; y <= yhi; ++y) {
                const bool face = zf || (y == cy - R) || (y == cy + R);
                const int rowb = (((b * NC) + z) * NC + y) * NC;
                if (face) {
                    const int st = cs[rowb + xlo], en = cs[rowb + xhi + 1];
                    for (int p = st; p < en; ++p) body(p);
                } else {
                    const int xm = cx - R, xp = cx + R;
                    if (xm >= 0) {
                        const int st = cs[rowb + xm], en = cs[rowb + xm + 1];
                        for (int p = st; p < en; ++p) body(p);
                    }
                    if (xp < NC) {
                        const int st = cs[rowb + xp], en = cs[rowb + xp + 1];
                        for (int p = st; p < en; ++p) body(p);
                    }
                }
            }
        }
    };

    // pass 1: top-16 keys via branchless med3 sorted insert (d[0] = max kept)
    float d[KNB];
#pragma unroll
    for (int k = 0; k < KNB; ++k) d[k] = FLT_BIG;

    int Rfin = 0;
    for (int R = 0;; ++R) {
        do_ring(R, [&](int p) {
            const float4 v = spp[p];
            const float x = fmaf(qx, v.x, fmaf(qy, v.y, fmaf(qz, v.z, v.w)));
#pragma unroll
            for (int k = 0; k < KNB - 1; ++k) d[k] = med3f(d[k], d[k + 1], x);
            d[KNB - 1] = fminf(d[KNB - 1], x);
        });
        if (R >= NC) { Rfin = R; break; }
        // min possible true d2 of any unprocessed point: distance to processed box
        const float bxl = fmaf((float)(cx - R), H, -LBOX);
        const float bxh = fmaf((float)(cx + R + 1), H, -LBOX);
        const float byl = fmaf((float)(cy - R), H, -LBOX);
        const float byh = fmaf((float)(cy + R + 1), H, -LBOX);
        const float bzl = fmaf((float)(cz - R), H, -LBOX);
        const float bzh = fmaf((float)(cz + R + 1), H, -LBOX);
        const float m = fminf(fminf(fminf(qx - bxl, bxh - qx), fminf(qy - byl, byh - qy)),
                              fminf(qz - bzl, bzh - qz));
        if (m > 0.f && (d[0] + qsq) <= fmaf(m, m, -1e-4f)) { Rfin = R; break; }
    }

    const float thr = d[0];
    const int qorig = sidx[s];
    const int obase = ((b << 13) + qorig) * KNB;

    // pass 2: collect strict (< thr) in walk order; ties (== thr) kept as the
    // smallest indices (index tie-break == reference top_k semantics).
    int cnt = 0;
    int ti[KNB];
#pragma unroll
    for (int k = 0; k < KNB; ++k) ti[k] = 0x7FFFFFFF;

    for (int R = 0; R <= Rfin; ++R) {
        do_ring(R, [&](int p) {
            const float4 v = spp[p];
            const float x = fmaf(qx, v.x, fmaf(qy, v.y, fmaf(qz, v.z, v.w)));
            if (x < thr && cnt < KNB) { knn[obase + cnt] = sidx[p]; ++cnt; }
            if (x == thr) {
                const int idx = sidx[p];
#pragma unroll
                for (int k = 0; k < KNB - 1; ++k) ti[k] = med3i(ti[k], ti[k + 1], idx);
                ti[KNB - 1] = min(ti[KNB - 1], idx);
            }
        });
    }
    const int need = KNB - cnt;
#pragma unroll
    for (int k = 0; k < KNB; ++k)
        if (k < need) knn[obase + cnt + k] = ti[KNB - 1 - k];
}

// ---------------- fused PT layer: per-edge MLPs + 16-lane shuffle softmax ----------------
__global__ __launch_bounds__(256) void pt_layer_f(const float* __restrict__ hin,
                                                  const float* __restrict__ pos,
                                                  const int* __restrict__ knn,
                                                  const float* __restrict__ wqkv,
                                                  const float* __restrict__ pw1,
                                                  const float* __restrict__ pb1,
                                                  const float* __restrict__ pw2,
                                                  const float* __restrict__ pb2,
                                                  const float* __restrict__ aw1,
                                                  const float* __restrict__ ab1,
                                                  const float* __restrict__ aw2,
                                                  const float* __restrict__ ab2,
                                                  float* __restrict__ hout,
                                                  const float* __restrict__ lw,
                                                  const float* __restrict__ lb,
                                                  float* __restrict__ out,
                                                  int last) {
    const int gt = blockIdx.x * 256 + threadIdx.x;   // edge id
    const int qg = gt >> 4;
    const int j  = gt & 15;
    const int b  = qg >> 13;
    const int jj = knn[qg * KNB + j] & (N_PTS - 1);
    const int g  = (b << 13) + jj;

    const float hi0 = hin[qg * 3 + 0], hi1 = hin[qg * 3 + 1], hi2 = hin[qg * 3 + 2];
    const float hj0 = hin[g * 3 + 0],  hj1 = hin[g * 3 + 1],  hj2 = hin[g * 3 + 2];
    const float rx = pos[qg * 3 + 0] - pos[g * 3 + 0];
    const float ry = pos[qg * 3 + 1] - pos[g * 3 + 1];
    const float rz = pos[qg * 3 + 2] - pos[g * 3 + 2];

    const float q0 = fmaf(hi0, wqkv[0], fmaf(hi1, wqkv[9],  hi2 * wqkv[18]));
    const float q1 = fmaf(hi0, wqkv[1], fmaf(hi1, wqkv[10], hi2 * wqkv[19]));
    const float q2 = fmaf(hi0, wqkv[2], fmaf(hi1, wqkv[11], hi2 * wqkv[20]));
    const float k0 = fmaf(hj0, wqkv[3], fmaf(hj1, wqkv[12], hj2 * wqkv[21]));
    const float k1 = fmaf(hj0, wqkv[4], fmaf(hj1, wqkv[13], hj2 * wqkv[22]));
    const float k2 = fmaf(hj0, wqkv[5], fmaf(hj1, wqkv[14], hj2 * wqkv[23]));
    const float v0 = fmaf(hj0, wqkv[6], fmaf(hj1, wqkv[15], hj2 * wqkv[24]));
    const float v1 = fmaf(hj0, wqkv[7], fmaf(hj1, wqkv[16], hj2 * wqkv[25]));
    const float v2 = fmaf(hj0, wqkv[8], fmaf(hj1, wqkv[17], hj2 * wqkv[26]));

    float e0 = pb2[0], e1 = pb2[1], e2 = pb2[2];
#pragma unroll
    for (int hh = 0; hh < 32; ++hh) {
        float t = fmaf(rx, pw1[hh], fmaf(ry, pw1[32 + hh], fmaf(rz, pw1[64 + hh], pb1[hh])));
        t = fmaxf(t, 0.0f);
        e0 = fmaf(t, pw2[hh * 3 + 0], e0);
        e1 = fmaf(t, pw2[hh * 3 + 1], e1);
        e2 = fmaf(t, pw2[hh * 3 + 2], e2);
    }

    const float x0 = q0 - k0 + e0;
    const float x1 = q1 - k1 + e1;
    const float x2 = q2 - k2 + e2;

    float s0 = ab2[0], s1 = ab2[1], s2 = ab2[2];
#pragma unroll
    for (int hh = 0; hh < 12; ++hh) {
        float t = fmaf(x0, aw1[hh], fmaf(x1, aw1[12 + hh], fmaf(x2, aw1[24 + hh], ab1[hh])));
        t = fmaxf(t, 0.0f);
        s0 = fmaf(t, aw2[hh * 3 + 0], s0);
        s1 = fmaf(t, aw2[hh * 3 + 1], s1);
        s2 = fmaf(t, aw2[hh * 3 + 2], s2);
    }

    const float w0 = v0 + e0, w1 = v1 + e1, w2 = v2 + e2;

    // softmax over the 16 lanes of this query (per channel), via shfl_xor
    float m0 = s0, m1 = s1, m2 = s2;
#pragma unroll
    for (int off = 1; off < 16; off <<= 1) {
        m0 = fmaxf(m0, __shfl_xor(m0, off));
        m1 = fmaxf(m1, __shfl_xor(m1, off));
        m2 = fmaxf(m2, __shfl_xor(m2, off));
    }
    const float ex0 = __expf(s0 - m0), ex1 = __expf(s1 - m1), ex2 = __expf(s2 - m2);
    float n0 = ex0 * w0, n1 = ex1 * w1, n2 = ex2 * w2;
    float den0 = ex0, den1 = ex1, den2 = ex2;
#pragma unroll
    for (int off = 1; off < 16; off <<= 1) {
        den0 += __shfl_xor(den0, off); n0 += __shfl_xor(n0, off);
        den1 += __shfl_xor(den1, off); n1 += __shfl_xor(n1, off);
        den2 += __shfl_xor(den2, off); n2 += __shfl_xor(n2, off);
    }

    if (j == 0) {
        const float h0 = 1.f / (1.f + __expf(-(n0 / den0)));
        const float h1 = 1.f / (1.f + __expf(-(n1 / den1)));
        const float h2 = 1.f / (1.f + __expf(-(n2 / den2)));
        if (!last) {
            hout[qg * 3 + 0] = h0;
            hout[qg * 3 + 1] = h1;
            hout[qg * 3 + 2] = h2;
        } else {
            const float o0 = fmaf(h0, lw[0], fmaf(h1, lw[2], fmaf(h2, lw[4], lb[0])));
            const float o1 = fmaf(h0, lw[1], fmaf(h1, lw[3], fmaf(h2, lw[5], lb[1])));
            const float mm = fmaxf(o0, o1);
            const float ea = __expf(o0 - mm), eb = __expf(o1 - mm);
            const float inv = 1.f / (ea + eb);
            out[qg * 2 + 0] = ea * inv;
            out[qg * 2 + 1] = eb * inv;
        }
    }
}

// ---------------- launch ----------------
extern "C" void kernel_launch(void* const* d_in, const int* in_sizes, int n_in,
                              void* d_out, int out_size, void* d_ws, size_t ws_size,
                              hipStream_t stream) {
    const float* feats = (const float*)d_in[0];
    const float* pos   = (const float*)d_in[1];
    const float* wqkv = (const float*)d_in[3];
    const float* pw1  = (const float*)d_in[4];
    const float* pb1  = (const float*)d_in[5];
    const float* pw2  = (const float*)d_in[6];
    const float* pb2  = (const float*)d_in[7];
    const float* aw1  = (const float*)d_in[8];
    const float* ab1  = (const float*)d_in[9];
    const float* aw2  = (const float*)d_in[10];
    const float* ab2  = (const float*)d_in[11];
    const float* lw   = (const float*)d_in[12];
    const float* lb   = (const float*)d_in[13];
    float* out = (float*)d_out;

    // workspace layout (16B-aligned chunks)
    size_t o = 0;
    auto take = [&](size_t bytes) { size_t r = o; o += (bytes + 15) & ~(size_t)15; return r; };
    const size_t o_cnt   = take((size_t)MCELL * 4);        // cnt (kcount)
    const size_t o_cnt2  = take((size_t)MCELL * 4);        // cnt2 (scatter cursors) - adjacent to cnt
    const size_t o_scan  = take((size_t)MCELL * 4);        // scanned (P1 out)
    const size_t o_cs    = take((size_t)(MCELL + 1) * 4);  // cell_start
    const size_t o_bsum  = take((size_t)256 * 4);
    const size_t o_cid   = take((size_t)NQ * 4);
    const size_t o_spp   = take((size_t)NQ * 16);
    const size_t o_sidx  = take((size_t)NQ * 4);
    const size_t o_knn   = take((size_t)NQ * KNB * 4);
    const size_t o_hA    = take((size_t)NQ * 3 * 4);
    const size_t o_hB    = take((size_t)NQ * 3 * 4);
    if (ws_size < o) return;

    char* ws = (char*)d_ws;
    int*    cnt   = (int*)(ws + o_cnt);
    int*    cnt2  = (int*)(ws + o_cnt2);
    int*    scan  = (int*)(ws + o_scan);
    int*    cs    = (int*)(ws + o_cs);
    int*    bsum  = (int*)(ws + o_bsum);
    int*    cid   = (int*)(ws + o_cid);
    float4* spp   = (float4*)(ws + o_spp);
    int*    sidx  = (int*)(ws + o_sidx);
    int*    knn   = (int*)(ws + o_knn);
    float*  hA    = (float*)(ws + o_hA);
    float*  hB    = (float*)(ws + o_hB);

    const int nscan = (MCELL + 1023) / 1024;   // 145

    // NOTE: cnt and cnt2 are adjacent but padded; zero them separately-sized
    kzero<<<(MCELL + 255) / 256, 256, 0, stream>>>(cnt, MCELL);
    kzero<<<(MCELL + 255) / 256, 256, 0, stream>>>(cnt2, MCELL);
    kcount<<<NQ / 256, 256, 0, stream>>>(pos, cnt, cid);
    kscan1<<<nscan, 1024, 0, stream>>>(cnt, scan, bsum);
    kscan2<<<nscan, 1024, 0, stream>>>(scan, bsum, cs);
    kscatter<<<NQ / 256, 256, 0, stream>>>(pos, cid, cs, cnt2, spp, sidx);
    ksearch<<<NQ / 64, 64, 0, stream>>>(spp, sidx, cs, knn);

    // layer 0: feats -> hA
    pt_layer_f<<<NQ * 16 / 256, 256, 0, stream>>>(feats, pos, knn,
        wqkv + 0, pw1 + 0, pb1 + 0, pw2 + 0, pb2 + 0,
        aw1 + 0, ab1 + 0, aw2 + 0, ab2 + 0,
        hA, lw, lb, out, 0);
    // layer 1: hA -> hB
    pt_layer_f<<<NQ * 16 / 256, 256, 0, stream>>>(hA, pos, knn,
        wqkv + 27, pw1 + 96, pb1 + 32, pw2 + 96, pb2 + 3,
        aw1 + 36, ab1 + 12, aw2 + 36, ab2 + 3,
        hB, lw, lb, out, 0);
    // layer 2: hB -> out (fused final head)
    pt_layer_f<<<NQ * 16 / 256, 256, 0, stream>>>(hB, pos, knn,
        wqkv + 54, pw1 + 192, pb1 + 64, pw2 + 192, pb2 + 6,
        aw1 + 72, ab1 + 24, aw2 + 72, ab2 + 6,
        hB, lw, lb, out, 1);
}

// Round 4
// 294.356 us; speedup vs baseline: 3.9719x; 3.9719x over previous
//
#include <hip/hip_runtime.h>
#include <math.h>

#define N_PTS 8192
#define BATCH 2
#define KNB 16
#define NQ (BATCH * N_PTS)          // 16384

// spatial grid
#define H    0.35f
#define INVH (1.0f / 0.35f)
#define NC   30
#define LBOX (0.5f * H * NC)        // 5.25
#define NCELL (NC * NC * NC)        // 27000
#define MCELL (2 * NCELL)           // 54000 (both batches)

typedef unsigned long long u64;

// ---------------- zero counts (cnt and cnt2 fused in one buffer) ----------------
__global__ __launch_bounds__(256) void kzero(int* __restrict__ p, int n) {
    const int i = blockIdx.x * 256 + threadIdx.x;
    if (i < n) p[i] = 0;
}

// ---------------- count points per cell ----------------
__global__ __launch_bounds__(256) void kcount(const float* __restrict__ pos,
                                              int* __restrict__ cnt,
                                              int* __restrict__ cellid) {
    const int g = blockIdx.x * 256 + threadIdx.x;      // global point id
    const int b = g >> 13;
    const float x = pos[g * 3 + 0], y = pos[g * 3 + 1], z = pos[g * 3 + 2];
    int cx = (int)floorf((x + LBOX) * INVH); cx = min(max(cx, 0), NC - 1);
    int cy = (int)floorf((y + LBOX) * INVH); cy = min(max(cy, 0), NC - 1);
    int cz = (int)floorf((z + LBOX) * INVH); cz = min(max(cz, 0), NC - 1);
    const int c = (((b * NC) + cz) * NC + cy) * NC + cx;
    cellid[g] = c;
    atomicAdd(&cnt[c], 1);
}

// ---------------- prefix sum, level 1 ----------------
__global__ __launch_bounds__(1024) void kscan1(const int* __restrict__ cnt,
                                               int* __restrict__ scanned,
                                               int* __restrict__ bsum) {
    __shared__ int sh[1024];
    const int t = threadIdx.x;
    const int idx = blockIdx.x * 1024 + t;
    int v = (idx < MCELL) ? cnt[idx] : 0;
    sh[t] = v;
    __syncthreads();
    for (int off = 1; off < 1024; off <<= 1) {
        const int add = (t >= off) ? sh[t - off] : 0;
        __syncthreads();
        sh[t] += add;
        __syncthreads();
    }
    if (idx < MCELL) scanned[idx] = sh[t];
    if (t == 1023) bsum[blockIdx.x] = sh[1023];
}

// ---------------- prefix sum, level 2 ----------------
__global__ __launch_bounds__(1024) void kscan2(const int* __restrict__ scanned,
                                               const int* __restrict__ bsum,
                                               int* __restrict__ cell_start) {
    __shared__ int soff;
    const int t = threadIdx.x;
    const int blk = blockIdx.x;
    const int idx = blk * 1024 + t;
    if (t == 0) {
        int s = 0;
        for (int k = 0; k < blk; ++k) s += bsum[k];
        soff = s;
    }
    __syncthreads();
    if (idx < MCELL) cell_start[idx + 1] = scanned[idx] + soff;
    if (idx == 0) cell_start[0] = 0;
}

// ---------------- scatter points into cell-sorted order ----------------
__global__ __launch_bounds__(256) void kscatter(const float* __restrict__ pos,
                                                const int* __restrict__ cellid,
                                                const int* __restrict__ cell_start,
                                                int* __restrict__ cnt2,
                                                float4* __restrict__ spp,
                                                int* __restrict__ sidx) {
    const int g = blockIdx.x * 256 + threadIdx.x;
    const int c = cellid[g];
    const int off = atomicAdd(&cnt2[c], 1);
    const int p = cell_start[c] + off;
    const float x = pos[g * 3 + 0], y = pos[g * 3 + 1], z = pos[g * 3 + 2];
    spp[p] = make_float4(-2.f * x, -2.f * y, -2.f * z, fmaf(x, x, fmaf(y, y, z * z)));
    sidx[p] = g & (N_PTS - 1);      // within-batch index
}

// ---------------- group-cooperative exact kNN: 16 lanes per query ----------------
// key(p) = |p|^2 - 2 q.p (monotone in d2); packed u64 = (sortable(key)<<32)|idx
// so u64-min order == (d2, idx) lexicographic == reference top_k tie-break.
__global__ __launch_bounds__(256) void ksearch(const float4* __restrict__ spp,
                                               const int* __restrict__ sidx,
                                               const int* __restrict__ cs,
                                               int* __restrict__ knn) {
    const int tid = threadIdx.x;
    const int li  = tid & 15;                          // lane within group
    const int sq  = blockIdx.x * 16 + (tid >> 4);      // sorted query slot
    const int b   = sq >> 13;

    const float4 me = spp[sq];
    const float qx = -0.5f * me.x, qy = -0.5f * me.y, qz = -0.5f * me.z;
    const float qsq = me.w;
    int cx = (int)floorf((qx + LBOX) * INVH); cx = min(max(cx, 0), NC - 1);
    int cy = (int)floorf((qy + LBOX) * INVH); cy = min(max(cy, 0), NC - 1);
    int cz = (int)floorf((qz + LBOX) * INVH); cz = min(max(cz, 0), NC - 1);

    // per-lane top-16 packed keys, descending (pk[0]=max kept, pk[15]=min)
    u64 pk[KNB];
#pragma unroll
    for (int k = 0; k < KNB; ++k) pk[k] = 0xFFFFFFFFFFFFFFFFull;

    auto insert = [&](int p) {
        const float4 v = spp[p];
        const float x = fmaf(qx, v.x, fmaf(qy, v.y, fmaf(qz, v.z, v.w)));
        unsigned u = __float_as_uint(x);
        u ^= (unsigned)((int)u >> 31) | 0x80000000u;
        const u64 key = ((u64)u << 32) | (unsigned)sidx[p];
        // branchless sorted insert (keep smallest 16)
#pragma unroll
        for (int s = 0; s < KNB; ++s) {
            const u64 ds1 = (s < KNB - 1) ? pk[s + 1] : 0ull;
            const bool c0 = key < pk[s];
            const bool c1 = key < ds1;
            pk[s] = c1 ? ds1 : (c0 ? key : pk[s]);
        }
    };

    bool done = false;
    int R = 0;
    while (true) {
        if (!done) {
            // walk ring R (cells at Chebyshev distance exactly R, grid-clipped)
            const int zlo = max(cz - R, 0), zhi = min(cz + R, NC - 1);
            const int ylo = max(cy - R, 0), yhi = min(cy + R, NC - 1);
            const int xlo = max(cx - R, 0), xhi = min(cx + R, NC - 1);
            for (int z = zlo; z <= zhi; ++z) {
                const bool zf = (z == cz - R) || (z == cz + R);
                for (int y = ylo; y <= yhi; ++y) {
                    const bool face = zf || (y == cy - R) || (y == cy + R);
                    const int rowb = (((b * NC) + z) * NC + y) * NC;
                    if (face) {
                        const int st = cs[rowb + xlo], en = cs[rowb + xhi + 1];
                        for (int p = st + li; p < en; p += 16) insert(p);
                    } else {
                        const int xm = cx - R, xp = cx + R;
                        if (xm >= 0) {
                            const int st = cs[rowb + xm], en = cs[rowb + xm + 1];
                            for (int p = st + li; p < en; p += 16) insert(p);
                        }
                        if (xp < NC) {
                            const int st = cs[rowb + xp], en = cs[rowb + xp + 1];
                            for (int p = st + li; p < en; p += 16) insert(p);
                        }
                    }
                }
            }
            if (R >= NC) {
                done = true;
            } else {
                // stop when >=16 seen keys are <= conservative box bound
                const float bxl = fmaf((float)(cx - R), H, -LBOX);
                const float bxh = fmaf((float)(cx + R + 1), H, -LBOX);
                const float byl = fmaf((float)(cy - R), H, -LBOX);
                const float byh = fmaf((float)(cy + R + 1), H, -LBOX);
                const float bzl = fmaf((float)(cz - R), H, -LBOX);
                const float bzh = fmaf((float)(cz + R + 1), H, -LBOX);
                const float m = fminf(fminf(fminf(qx - bxl, bxh - qx),
                                            fminf(qy - byl, byh - qy)),
                                      fminf(qz - bzl, bzh - qz));
                if (m > 0.f) {
                    const float Bf = fmaf(m, m, -1e-4f) - qsq;
                    unsigned Bu = __float_as_uint(Bf);
                    Bu ^= (unsigned)((int)Bu >> 31) | 0x80000000u;
                    int cnt = 0;
#pragma unroll
                    for (int k = 0; k < KNB; ++k) cnt += ((unsigned)(pk[k] >> 32) <= Bu);
#pragma unroll
                    for (int off = 1; off < 16; off <<= 1) cnt += __shfl_xor(cnt, off);
                    if (cnt >= KNB) done = true;
                }
            }
        }
        if (__all(done)) break;
        ++R;
    }

    // merge 16 lane-local sorted-desc arrays -> global top-16 (bitonic, 4 rounds)
#pragma unroll
    for (int mm = 1; mm <= 8; mm <<= 1) {
        u64 L[KNB];
#pragma unroll
        for (int i = 0; i < KNB; ++i) {
            const u64 a = pk[i];
            const u64 c = __shfl_xor(pk[KNB - 1 - i], mm);
            L[i] = a < c ? a : c;           // lower half of bitonic split
        }
        // resort bitonic L descending
#pragma unroll
        for (int d = 8; d >= 1; d >>= 1) {
#pragma unroll
            for (int i = 0; i < KNB; ++i) {
                if ((i & d) == 0) {
                    const u64 hi = L[i] > L[i | d] ? L[i] : L[i | d];
                    const u64 lo = L[i] > L[i | d] ? L[i | d] : L[i];
                    L[i] = hi; L[i | d] = lo;
                }
            }
        }
#pragma unroll
        for (int i = 0; i < KNB; ++i) pk[i] = L[i];
    }

    // every lane holds the full result; lane li writes element li (static select)
    const int qorig = sidx[sq];
    const int obase = ((b << 13) + qorig) * KNB;
    u64 sel = pk[0];
#pragma unroll
    for (int s = 1; s < KNB; ++s) sel = (li == s) ? pk[s] : sel;
    knn[obase + li] = (int)(unsigned)(sel & 0xFFFFFFFFull);
}

// ---------------- fused PT layer: per-edge MLPs + 16-lane shuffle softmax ----------------
__global__ __launch_bounds__(256) void pt_layer_f(const float* __restrict__ hin,
                                                  const float* __restrict__ pos,
                                                  const int* __restrict__ knn,
                                                  const float* __restrict__ wqkv,
                                                  const float* __restrict__ pw1,
                                                  const float* __restrict__ pb1,
                                                  const float* __restrict__ pw2,
                                                  const float* __restrict__ pb2,
                                                  const float* __restrict__ aw1,
                                                  const float* __restrict__ ab1,
                                                  const float* __restrict__ aw2,
                                                  const float* __restrict__ ab2,
                                                  float* __restrict__ hout,
                                                  const float* __restrict__ lw,
                                                  const float* __restrict__ lb,
                                                  float* __restrict__ out,
                                                  int last) {
    const int gt = blockIdx.x * 256 + threadIdx.x;   // edge id
    const int qg = gt >> 4;
    const int j  = gt & 15;
    const int b  = qg >> 13;
    const int jj = knn[qg * KNB + j] & (N_PTS - 1);
    const int g  = (b << 13) + jj;

    const float hi0 = hin[qg * 3 + 0], hi1 = hin[qg * 3 + 1], hi2 = hin[qg * 3 + 2];
    const float hj0 = hin[g * 3 + 0],  hj1 = hin[g * 3 + 1],  hj2 = hin[g * 3 + 2];
    const float rx = pos[qg * 3 + 0] - pos[g * 3 + 0];
    const float ry = pos[qg * 3 + 1] - pos[g * 3 + 1];
    const float rz = pos[qg * 3 + 2] - pos[g * 3 + 2];

    const float q0 = fmaf(hi0, wqkv[0], fmaf(hi1, wqkv[9],  hi2 * wqkv[18]));
    const float q1 = fmaf(hi0, wqkv[1], fmaf(hi1, wqkv[10], hi2 * wqkv[19]));
    const float q2 = fmaf(hi0, wqkv[2], fmaf(hi1, wqkv[11], hi2 * wqkv[20]));
    const float k0 = fmaf(hj0, wqkv[3], fmaf(hj1, wqkv[12], hj2 * wqkv[21]));
    const float k1 = fmaf(hj0, wqkv[4], fmaf(hj1, wqkv[13], hj2 * wqkv[22]));
    const float k2 = fmaf(hj0, wqkv[5], fmaf(hj1, wqkv[14], hj2 * wqkv[23]));
    const float v0 = fmaf(hj0, wqkv[6], fmaf(hj1, wqkv[15], hj2 * wqkv[24]));
    const float v1 = fmaf(hj0, wqkv[7], fmaf(hj1, wqkv[16], hj2 * wqkv[25]));
    const float v2 = fmaf(hj0, wqkv[8], fmaf(hj1, wqkv[17], hj2 * wqkv[26]));

    float e0 = pb2[0], e1 = pb2[1], e2 = pb2[2];
#pragma unroll
    for (int hh = 0; hh < 32; ++hh) {
        float t = fmaf(rx, pw1[hh], fmaf(ry, pw1[32 + hh], fmaf(rz, pw1[64 + hh], pb1[hh])));
        t = fmaxf(t, 0.0f);
        e0 = fmaf(t, pw2[hh * 3 + 0], e0);
        e1 = fmaf(t, pw2[hh * 3 + 1], e1);
        e2 = fmaf(t, pw2[hh * 3 + 2], e2);
    }

    const float x0 = q0 - k0 + e0;
    const float x1 = q1 - k1 + e1;
    const float x2 = q2 - k2 + e2;

    float s0 = ab2[0], s1 = ab2[1], s2 = ab2[2];
#pragma unroll
    for (int hh = 0; hh < 12; ++hh) {
        float t = fmaf(x0, aw1[hh], fmaf(x1, aw1[12 + hh], fmaf(x2, aw1[24 + hh], ab1[hh])));
        t = fmaxf(t, 0.0f);
        s0 = fmaf(t, aw2[hh * 3 + 0], s0);
        s1 = fmaf(t, aw2[hh * 3 + 1], s1);
        s2 = fmaf(t, aw2[hh * 3 + 2], s2);
    }

    const float w0 = v0 + e0, w1 = v1 + e1, w2 = v2 + e2;

    float m0 = s0, m1 = s1, m2 = s2;
#pragma unroll
    for (int off = 1; off < 16; off <<= 1) {
        m0 = fmaxf(m0, __shfl_xor(m0, off));
        m1 = fmaxf(m1, __shfl_xor(m1, off));
        m2 = fmaxf(m2, __shfl_xor(m2, off));
    }
    const float ex0 = __expf(s0 - m0), ex1 = __expf(s1 - m1), ex2 = __expf(s2 - m2);
    float n0 = ex0 * w0, n1 = ex1 * w1, n2 = ex2 * w2;
    float den0 = ex0, den1 = ex1, den2 = ex2;
#pragma unroll
    for (int off = 1; off < 16; off <<= 1) {
        den0 += __shfl_xor(den0, off); n0 += __shfl_xor(n0, off);
        den1 += __shfl_xor(den1, off); n1 += __shfl_xor(n1, off);
        den2 += __shfl_xor(den2, off); n2 += __shfl_xor(n2, off);
    }

    if (j == 0) {
        const float h0 = 1.f / (1.f + __expf(-(n0 / den0)));
        const float h1 = 1.f / (1.f + __expf(-(n1 / den1)));
        const float h2 = 1.f / (1.f + __expf(-(n2 / den2)));
        if (!last) {
            hout[qg * 3 + 0] = h0;
            hout[qg * 3 + 1] = h1;
            hout[qg * 3 + 2] = h2;
        } else {
            const float o0 = fmaf(h0, lw[0], fmaf(h1, lw[2], fmaf(h2, lw[4], lb[0])));
            const float o1 = fmaf(h0, lw[1], fmaf(h1, lw[3], fmaf(h2, lw[5], lb[1])));
            const float mm = fmaxf(o0, o1);
            const float ea = __expf(o0 - mm), eb = __expf(o1 - mm);
            const float inv = 1.f / (ea + eb);
            out[qg * 2 + 0] = ea * inv;
            out[qg * 2 + 1] = eb * inv;
        }
    }
}

// ---------------- launch ----------------
extern "C" void kernel_launch(void* const* d_in, const int* in_sizes, int n_in,
                              void* d_out, int out_size, void* d_ws, size_t ws_size,
                              hipStream_t stream) {
    const float* feats = (const float*)d_in[0];
    const float* pos   = (const float*)d_in[1];
    const float* wqkv = (const float*)d_in[3];
    const float* pw1  = (const float*)d_in[4];
    const float* pb1  = (const float*)d_in[5];
    const float* pw2  = (const float*)d_in[6];
    const float* pb2  = (const float*)d_in[7];
    const float* aw1  = (const float*)d_in[8];
    const float* ab1  = (const float*)d_in[9];
    const float* aw2  = (const float*)d_in[10];
    const float* ab2  = (const float*)d_in[11];
    const float* lw   = (const float*)d_in[12];
    const float* lb   = (const float*)d_in[13];
    float* out = (float*)d_out;

    size_t o = 0;
    auto take = [&](size_t bytes) { size_t r = o; o += (bytes + 15) & ~(size_t)15; return r; };
    const size_t o_cnt   = take((size_t)2 * MCELL * 4);    // cnt | cnt2 (fused zeroing)
    const size_t o_scan  = take((size_t)MCELL * 4);
    const size_t o_cs    = take((size_t)(MCELL + 1) * 4);
    const size_t o_bsum  = take((size_t)256 * 4);
    const size_t o_cid   = take((size_t)NQ * 4);
    const size_t o_spp   = take((size_t)NQ * 16);
    const size_t o_sidx  = take((size_t)NQ * 4);
    const size_t o_knn   = take((size_t)NQ * KNB * 4);
    const size_t o_hA    = take((size_t)NQ * 3 * 4);
    const size_t o_hB    = take((size_t)NQ * 3 * 4);
    if (ws_size < o) return;

    char* ws = (char*)d_ws;
    int*    cnt   = (int*)(ws + o_cnt);
    int*    cnt2  = cnt + MCELL;
    int*    scan  = (int*)(ws + o_scan);
    int*    cs    = (int*)(ws + o_cs);
    int*    bsum  = (int*)(ws + o_bsum);
    int*    cid   = (int*)(ws + o_cid);
    float4* spp   = (float4*)(ws + o_spp);
    int*    sidx  = (int*)(ws + o_sidx);
    int*    knn   = (int*)(ws + o_knn);
    float*  hA    = (float*)(ws + o_hA);
    float*  hB    = (float*)(ws + o_hB);

    const int nscan = (MCELL + 1023) / 1024;   // 53

    kzero<<<(2 * MCELL + 255) / 256, 256, 0, stream>>>(cnt, 2 * MCELL);
    kcount<<<NQ / 256, 256, 0, stream>>>(pos, cnt, cid);
    kscan1<<<nscan, 1024, 0, stream>>>(cnt, scan, bsum);
    kscan2<<<nscan, 1024, 0, stream>>>(scan, bsum, cs);
    kscatter<<<NQ / 256, 256, 0, stream>>>(pos, cid, cs, cnt2, spp, sidx);
    ksearch<<<NQ / 16, 256, 0, stream>>>(spp, sidx, cs, knn);

    // layer 0: feats -> hA
    pt_layer_f<<<NQ * 16 / 256, 256, 0, stream>>>(feats, pos, knn,
        wqkv + 0, pw1 + 0, pb1 + 0, pw2 + 0, pb2 + 0,
        aw1 + 0, ab1 + 0, aw2 + 0, ab2 + 0,
        hA, lw, lb, out, 0);
    // layer 1: hA -> hB
    pt_layer_f<<<NQ * 16 / 256, 256, 0, stream>>>(hA, pos, knn,
        wqkv + 27, pw1 + 96, pb1 + 32, pw2 + 96, pb2 + 3,
        aw1 + 36, ab1 + 12, aw2 + 36, ab2 + 3,
        hB, lw, lb, out, 0);
    // layer 2: hB -> out (fused final head)
    pt_layer_f<<<NQ * 16 / 256, 256, 0, stream>>>(hB, pos, knn,
        wqkv + 54, pw1 + 192, pb1 + 64, pw2 + 192, pb2 + 6,
        aw1 + 72, ab1 + 24, aw2 + 72, ab2 + 6,
        hB, lw, lb, out, 1);
}

// Round 5
// 183.769 us; speedup vs baseline: 6.3621x; 1.6018x over previous
//
#include <hip/hip_runtime.h>
#include <math.h>

#define N_PTS 8192
#define BATCH 2
#define KNB 16
#define NQ (BATCH * N_PTS)          // 16384

// spatial grid
#define H    0.35f
#define INVH (1.0f / 0.35f)
#define NC   30
#define LBOX (0.5f * H * NC)        // 5.25
#define NCELL (NC * NC * NC)        // 27000
#define MCELL (2 * NCELL)           // 54000 (both batches)
#define RMAXF 2                     // fast-path max ring
#define SLOWG 1024                  // slow-path grid (blocks of 64)

typedef unsigned long long u64;

__device__ __forceinline__ float med3f(float a, float b, float c) {
#if __has_builtin(__builtin_amdgcn_fmed3f)
    return __builtin_amdgcn_fmed3f(a, b, c);
#else
    return fmaxf(fminf(a, b), fminf(fmaxf(a, b), c));
#endif
}

__device__ __forceinline__ unsigned sortable(float x) {
    unsigned u = __float_as_uint(x);
    return u ^ ((unsigned)((int)u >> 31) | 0x80000000u);
}

// ---------------- zero counters ----------------
__global__ __launch_bounds__(256) void kzero(int* __restrict__ p, int n) {
    const int i = blockIdx.x * 256 + threadIdx.x;
    if (i < n) p[i] = 0;
}

// ---------------- count points per cell ----------------
__global__ __launch_bounds__(256) void kcount(const float* __restrict__ pos,
                                              int* __restrict__ cnt,
                                              int* __restrict__ cellid) {
    const int g = blockIdx.x * 256 + threadIdx.x;
    const int b = g >> 13;
    const float x = pos[g * 3 + 0], y = pos[g * 3 + 1], z = pos[g * 3 + 2];
    int cx = (int)floorf((x + LBOX) * INVH); cx = min(max(cx, 0), NC - 1);
    int cy = (int)floorf((y + LBOX) * INVH); cy = min(max(cy, 0), NC - 1);
    int cz = (int)floorf((z + LBOX) * INVH); cz = min(max(cz, 0), NC - 1);
    const int c = (((b * NC) + cz) * NC + cy) * NC + cx;
    cellid[g] = c;
    atomicAdd(&cnt[c], 1);
}

// ---------------- prefix sum, level 1 ----------------
__global__ __launch_bounds__(1024) void kscan1(const int* __restrict__ cnt,
                                               int* __restrict__ scanned,
                                               int* __restrict__ bsum) {
    __shared__ int sh[1024];
    const int t = threadIdx.x;
    const int idx = blockIdx.x * 1024 + t;
    int v = (idx < MCELL) ? cnt[idx] : 0;
    sh[t] = v;
    __syncthreads();
    for (int off = 1; off < 1024; off <<= 1) {
        const int add = (t >= off) ? sh[t - off] : 0;
        __syncthreads();
        sh[t] += add;
        __syncthreads();
    }
    if (idx < MCELL) scanned[idx] = sh[t];
    if (t == 1023) bsum[blockIdx.x] = sh[1023];
}

// ---------------- prefix sum, level 2 ----------------
__global__ __launch_bounds__(1024) void kscan2(const int* __restrict__ scanned,
                                               const int* __restrict__ bsum,
                                               int* __restrict__ cell_start) {
    __shared__ int soff;
    const int t = threadIdx.x;
    const int blk = blockIdx.x;
    const int idx = blk * 1024 + t;
    if (t == 0) {
        int s = 0;
        for (int k = 0; k < blk; ++k) s += bsum[k];
        soff = s;
    }
    __syncthreads();
    if (idx < MCELL) cell_start[idx + 1] = scanned[idx] + soff;
    if (idx == 0) cell_start[0] = 0;
}

// ---------------- scatter points into cell-sorted order ----------------
__global__ __launch_bounds__(256) void kscatter(const float* __restrict__ pos,
                                                const int* __restrict__ cellid,
                                                const int* __restrict__ cell_start,
                                                int* __restrict__ cnt2,
                                                float4* __restrict__ spp,
                                                int* __restrict__ sidx) {
    const int g = blockIdx.x * 256 + threadIdx.x;
    const int c = cellid[g];
    const int off = atomicAdd(&cnt2[c], 1);
    const int p = cell_start[c] + off;
    const float x = pos[g * 3 + 0], y = pos[g * 3 + 1], z = pos[g * 3 + 2];
    spp[p] = make_float4(-2.f * x, -2.f * y, -2.f * z, fmaf(x, x, fmaf(y, y, z * z)));
    sidx[p] = g & (N_PTS - 1);
}

// ---------------- fast kNN: 16 lanes/query, rings R<=2, else overflow ----------------
__global__ __launch_bounds__(64) void ksearch_fast(const float4* __restrict__ spp,
                                                   const int* __restrict__ sidx,
                                                   const int* __restrict__ cs,
                                                   int* __restrict__ knn,
                                                   int* __restrict__ ovf_list,
                                                   int* __restrict__ ovf_cnt) {
    const int tid = threadIdx.x;
    const int li  = tid & 15;
    const int sq  = blockIdx.x * 4 + (tid >> 4);
    const int b   = sq >> 13;

    const float4 me = spp[sq];
    const float qx = -0.5f * me.x, qy = -0.5f * me.y, qz = -0.5f * me.z;
    const float qsq = me.w;
    int cx = (int)floorf((qx + LBOX) * INVH); cx = min(max(cx, 0), NC - 1);
    int cy = (int)floorf((qy + LBOX) * INVH); cy = min(max(cy, 0), NC - 1);
    int cz = (int)floorf((qz + LBOX) * INVH); cz = min(max(cz, 0), NC - 1);

    auto do_ring = [&](int R, auto&& body) {
        const int zlo = max(cz - R, 0), zhi = min(cz + R, NC - 1);
        const int ylo = max(cy - R, 0), yhi = min(cy + R, NC - 1);
        const int xlo = max(cx - R, 0), xhi = min(cx + R, NC - 1);
        for (int z = zlo; z <= zhi; ++z) {
            const bool zf = (z == cz - R) || (z == cz + R);
            for (int y = ylo; y <= yhi; ++y) {
                const bool face = zf || (y == cy - R) || (y == cy + R);
                const int rowb = (((b * NC) + z) * NC + y) * NC;
                if (face) {
                    const int st = cs[rowb + xlo], en = cs[rowb + xhi + 1];
                    for (int p = st + li; p < en; p += 16) body(p);
                } else {
                    const int xm = cx - R, xp = cx + R;
                    if (xm >= 0) {
                        const int st = cs[rowb + xm], en = cs[rowb + xm + 1];
                        for (int p = st + li; p < en; p += 16) body(p);
                    }
                    if (xp < NC) {
                        const int st = cs[rowb + xp], en = cs[rowb + xp + 1];
                        for (int p = st + li; p < en; p += 16) body(p);
                    }
                }
            }
        }
    };

    // ---- pass 1: per-lane top-16 float keys (guarded med3 chain) ----
    float d[KNB];
#pragma unroll
    for (int k = 0; k < KNB; ++k) d[k] = 3.4e38f;

    auto scan1 = [&](int p) {
        const float4 v = spp[p];
        const float x = fmaf(qx, v.x, fmaf(qy, v.y, fmaf(qz, v.z, v.w)));
        if (x < d[0]) {
#pragma unroll
            for (int s = 0; s < KNB - 1; ++s) d[s] = med3f(d[s], d[s + 1], x);
            d[KNB - 1] = fminf(d[KNB - 1], x);
        }
    };

    int Rfin = -1;
    for (int R = 0; R <= RMAXF; ++R) {
        do_ring(R, scan1);
        const float bxl = fmaf((float)(cx - R), H, -LBOX);
        const float bxh = fmaf((float)(cx + R + 1), H, -LBOX);
        const float byl = fmaf((float)(cy - R), H, -LBOX);
        const float byh = fmaf((float)(cy + R + 1), H, -LBOX);
        const float bzl = fmaf((float)(cz - R), H, -LBOX);
        const float bzh = fmaf((float)(cz + R + 1), H, -LBOX);
        const float m = fminf(fminf(fminf(qx - bxl, bxh - qx),
                                    fminf(qy - byl, byh - qy)),
                              fminf(qz - bzl, bzh - qz));
        if (m > 0.f) {
            const float Bf = fmaf(m, m, -1e-4f) - qsq;
            int c = 0;
#pragma unroll
            for (int k = 0; k < KNB; ++k) c += (d[k] <= Bf) ? 1 : 0;
#pragma unroll
            for (int off = 1; off < 16; off <<= 1) c += __shfl_xor(c, off);
            if (c >= KNB) { Rfin = R; break; }
        }
    }

    if (Rfin < 0) {
        if (li == 0) { const int s2 = atomicAdd(ovf_cnt, 1); ovf_list[s2] = sq; }
        return;
    }

    // ---- merge per-lane float tops -> global top-16 keys (all lanes) ----
#pragma unroll
    for (int mm = 1; mm <= 8; mm <<= 1) {
        float L[KNB];
#pragma unroll
        for (int i = 0; i < KNB; ++i)
            L[i] = fminf(d[i], __shfl_xor(d[KNB - 1 - i], mm));
#pragma unroll
        for (int dd = 8; dd >= 1; dd >>= 1) {
#pragma unroll
            for (int i = 0; i < KNB; ++i) {
                if ((i & dd) == 0) {
                    const float hi = fmaxf(L[i], L[i | dd]);
                    const float lo = fminf(L[i], L[i | dd]);
                    L[i] = hi; L[i | dd] = lo;
                }
            }
        }
#pragma unroll
        for (int i = 0; i < KNB; ++i) d[i] = L[i];
    }
    const float thr = d[0];           // exact global 16th-smallest key

    // ---- pass 2 (cache-hot): exact (key,idx) top-16 among x <= thr ----
    u64 pk[KNB];
#pragma unroll
    for (int k = 0; k < KNB; ++k) pk[k] = 0xFFFFFFFFFFFFFFFFull;

    auto scan2 = [&](int p) {
        const float4 v = spp[p];
        const float x = fmaf(qx, v.x, fmaf(qy, v.y, fmaf(qz, v.z, v.w)));
        if (x <= thr) {
            const u64 key = ((u64)sortable(x) << 32) | (unsigned)sidx[p];
            if (key < pk[0]) {
#pragma unroll
                for (int s = 0; s < KNB; ++s) {
                    const u64 ds1 = (s < KNB - 1) ? pk[s + 1] : 0ull;
                    const bool c0 = key < pk[s];
                    const bool c1 = key < ds1;
                    pk[s] = c1 ? ds1 : (c0 ? key : pk[s]);
                }
            }
        }
    };
    for (int R = 0; R <= Rfin; ++R) do_ring(R, scan2);

    // ---- u64 16-lane bitonic merge -> exact global top-16 (key,idx) ----
#pragma unroll
    for (int mm = 1; mm <= 8; mm <<= 1) {
        u64 L[KNB];
#pragma unroll
        for (int i = 0; i < KNB; ++i) {
            const u64 a = pk[i];
            const u64 c = __shfl_xor(pk[KNB - 1 - i], mm);
            L[i] = a < c ? a : c;
        }
#pragma unroll
        for (int dd = 8; dd >= 1; dd >>= 1) {
#pragma unroll
            for (int i = 0; i < KNB; ++i) {
                if ((i & dd) == 0) {
                    const u64 hi = L[i] > L[i | dd] ? L[i] : L[i | dd];
                    const u64 lo = L[i] > L[i | dd] ? L[i | dd] : L[i];
                    L[i] = hi; L[i | dd] = lo;
                }
            }
        }
#pragma unroll
        for (int i = 0; i < KNB; ++i) pk[i] = L[i];
    }

    const int qorig = sidx[sq];
    const int obase = ((b << 13) + qorig) * KNB;
    u64 sel = pk[0];
#pragma unroll
    for (int s = 1; s < KNB; ++s) sel = (li == s) ? pk[s] : sel;
    knn[obase + li] = (int)(unsigned)(sel & 0xFFFFFFFFull);
}

// ---------------- slow kNN: one wave per overflow query, one ring-row per lane ----------------
__global__ __launch_bounds__(64) void ksearch_slow(const float4* __restrict__ spp,
                                                   const int* __restrict__ sidx,
                                                   const int* __restrict__ cs,
                                                   int* __restrict__ knn,
                                                   const int* __restrict__ ovf_list,
                                                   const int* __restrict__ ovf_cnt) {
    const int lane = threadIdx.x;
    const int nov = *ovf_cnt;

    for (int w = blockIdx.x; w < nov; w += SLOWG) {
        const int sq = ovf_list[w];
        const int b  = sq >> 13;
        const float4 me = spp[sq];
        const float qx = -0.5f * me.x, qy = -0.5f * me.y, qz = -0.5f * me.z;
        const float qsq = me.w;
        int cx = (int)floorf((qx + LBOX) * INVH); cx = min(max(cx, 0), NC - 1);
        int cy = (int)floorf((qy + LBOX) * INVH); cy = min(max(cy, 0), NC - 1);
        int cz = (int)floorf((qz + LBOX) * INVH); cz = min(max(cz, 0), NC - 1);

        u64 pk[KNB];
#pragma unroll
        for (int k = 0; k < KNB; ++k) pk[k] = 0xFFFFFFFFFFFFFFFFull;

        auto ins = [&](int p) {
            const float4 v = spp[p];
            const float x = fmaf(qx, v.x, fmaf(qy, v.y, fmaf(qz, v.z, v.w)));
            const u64 key = ((u64)sortable(x) << 32) | (unsigned)sidx[p];
            if (key < pk[0]) {
#pragma unroll
                for (int s = 0; s < KNB; ++s) {
                    const u64 ds1 = (s < KNB - 1) ? pk[s + 1] : 0ull;
                    const bool c0 = key < pk[s];
                    const bool c1 = key < ds1;
                    pk[s] = c1 ? ds1 : (c0 ? key : pk[s]);
                }
            }
        };

        bool fin = false;
        for (int R = 0; !fin; ++R) {
            const int W = 2 * R + 1;
            const int nrows = W * W;
            for (int t = lane; t < nrows; t += 64) {
                const int dz = t / W - R;
                const int dy = t - (dz + R) * W - R;
                const int z = cz + dz, y = cy + dy;
                if (z < 0 || z >= NC || y < 0 || y >= NC) continue;
                const bool face = (dz == -R) || (dz == R) || (dy == -R) || (dy == R);
                const int rowb = (((b * NC) + z) * NC + y) * NC;
                if (face) {
                    const int xlo = max(cx - R, 0), xhi = min(cx + R, NC - 1);
                    const int st = cs[rowb + xlo], en = cs[rowb + xhi + 1];
                    for (int p = st; p < en; ++p) ins(p);
                } else {
                    const int xm = cx - R, xp = cx + R;
                    if (xm >= 0) {
                        const int st = cs[rowb + xm], en = cs[rowb + xm + 1];
                        for (int p = st; p < en; ++p) ins(p);
                    }
                    if (xp < NC) {
                        const int st = cs[rowb + xp], en = cs[rowb + xp + 1];
                        for (int p = st; p < en; ++p) ins(p);
                    }
                }
            }
            if (R >= NC) {
                fin = true;
            } else {
                const float bxl = fmaf((float)(cx - R), H, -LBOX);
                const float bxh = fmaf((float)(cx + R + 1), H, -LBOX);
                const float byl = fmaf((float)(cy - R), H, -LBOX);
                const float byh = fmaf((float)(cy + R + 1), H, -LBOX);
                const float bzl = fmaf((float)(cz - R), H, -LBOX);
                const float bzh = fmaf((float)(cz + R + 1), H, -LBOX);
                const float m = fminf(fminf(fminf(qx - bxl, bxh - qx),
                                            fminf(qy - byl, byh - qy)),
                                      fminf(qz - bzl, bzh - qz));
                if (m > 0.f) {
                    const float Bf = fmaf(m, m, -1e-4f) - qsq;
                    unsigned Bu = sortable(Bf);
                    int c = 0;
#pragma unroll
                    for (int k = 0; k < KNB; ++k) c += ((unsigned)(pk[k] >> 32) <= Bu) ? 1 : 0;
#pragma unroll
                    for (int off = 1; off < 64; off <<= 1) c += __shfl_xor(c, off);
                    if (c >= KNB) fin = true;
                }
            }
        }

        // 64-lane bitonic merge (6 rounds)
#pragma unroll
        for (int mm = 1; mm <= 32; mm <<= 1) {
            u64 L[KNB];
#pragma unroll
            for (int i = 0; i < KNB; ++i) {
                const u64 a = pk[i];
                const u64 c = __shfl_xor(pk[KNB - 1 - i], mm);
                L[i] = a < c ? a : c;
            }
#pragma unroll
            for (int dd = 8; dd >= 1; dd >>= 1) {
#pragma unroll
                for (int i = 0; i < KNB; ++i) {
                    if ((i & dd) == 0) {
                        const u64 hi = L[i] > L[i | dd] ? L[i] : L[i | dd];
                        const u64 lo = L[i] > L[i | dd] ? L[i | dd] : L[i];
                        L[i] = hi; L[i | dd] = lo;
                    }
                }
            }
#pragma unroll
            for (int i = 0; i < KNB; ++i) pk[i] = L[i];
        }

        const int qorig = sidx[sq];
        const int obase = ((b << 13) + qorig) * KNB;
        u64 sel = pk[0];
#pragma unroll
        for (int s = 1; s < KNB; ++s) sel = (lane == s) ? pk[s] : sel;
        if (lane < KNB) knn[obase + lane] = (int)(unsigned)(sel & 0xFFFFFFFFull);
    }
}

// ---------------- fused PT layer: per-edge MLPs + 16-lane shuffle softmax ----------------
__global__ __launch_bounds__(256) void pt_layer_f(const float* __restrict__ hin,
                                                  const float* __restrict__ pos,
                                                  const int* __restrict__ knn,
                                                  const float* __restrict__ wqkv,
                                                  const float* __restrict__ pw1,
                                                  const float* __restrict__ pb1,
                                                  const float* __restrict__ pw2,
                                                  const float* __restrict__ pb2,
                                                  const float* __restrict__ aw1,
                                                  const float* __restrict__ ab1,
                                                  const float* __restrict__ aw2,
                                                  const float* __restrict__ ab2,
                                                  float* __restrict__ hout,
                                                  const float* __restrict__ lw,
                                                  const float* __restrict__ lb,
                                                  float* __restrict__ out,
                                                  int last) {
    const int gt = blockIdx.x * 256 + threadIdx.x;
    const int qg = gt >> 4;
    const int j  = gt & 15;
    const int b  = qg >> 13;
    const int jj = knn[qg * KNB + j] & (N_PTS - 1);
    const int g  = (b << 13) + jj;

    const float hi0 = hin[qg * 3 + 0], hi1 = hin[qg * 3 + 1], hi2 = hin[qg * 3 + 2];
    const float hj0 = hin[g * 3 + 0],  hj1 = hin[g * 3 + 1],  hj2 = hin[g * 3 + 2];
    const float rx = pos[qg * 3 + 0] - pos[g * 3 + 0];
    const float ry = pos[qg * 3 + 1] - pos[g * 3 + 1];
    const float rz = pos[qg * 3 + 2] - pos[g * 3 + 2];

    const float q0 = fmaf(hi0, wqkv[0], fmaf(hi1, wqkv[9],  hi2 * wqkv[18]));
    const float q1 = fmaf(hi0, wqkv[1], fmaf(hi1, wqkv[10], hi2 * wqkv[19]));
    const float q2 = fmaf(hi0, wqkv[2], fmaf(hi1, wqkv[11], hi2 * wqkv[20]));
    const float k0 = fmaf(hj0, wqkv[3], fmaf(hj1, wqkv[12], hj2 * wqkv[21]));
    const float k1 = fmaf(hj0, wqkv[4], fmaf(hj1, wqkv[13], hj2 * wqkv[22]));
    const float k2 = fmaf(hj0, wqkv[5], fmaf(hj1, wqkv[14], hj2 * wqkv[23]));
    const float v0 = fmaf(hj0, wqkv[6], fmaf(hj1, wqkv[15], hj2 * wqkv[24]));
    const float v1 = fmaf(hj0, wqkv[7], fmaf(hj1, wqkv[16], hj2 * wqkv[25]));
    const float v2 = fmaf(hj0, wqkv[8], fmaf(hj1, wqkv[17], hj2 * wqkv[26]));

    float e0 = pb2[0], e1 = pb2[1], e2 = pb2[2];
#pragma unroll
    for (int hh = 0; hh < 32; ++hh) {
        float t = fmaf(rx, pw1[hh], fmaf(ry, pw1[32 + hh], fmaf(rz, pw1[64 + hh], pb1[hh])));
        t = fmaxf(t, 0.0f);
        e0 = fmaf(t, pw2[hh * 3 + 0], e0);
        e1 = fmaf(t, pw2[hh * 3 + 1], e1);
        e2 = fmaf(t, pw2[hh * 3 + 2], e2);
    }

    const float x0 = q0 - k0 + e0;
    const float x1 = q1 - k1 + e1;
    const float x2 = q2 - k2 + e2;

    float s0 = ab2[0], s1 = ab2[1], s2 = ab2[2];
#pragma unroll
    for (int hh = 0; hh < 12; ++hh) {
        float t = fmaf(x0, aw1[hh], fmaf(x1, aw1[12 + hh], fmaf(x2, aw1[24 + hh], ab1[hh])));
        t = fmaxf(t, 0.0f);
        s0 = fmaf(t, aw2[hh * 3 + 0], s0);
        s1 = fmaf(t, aw2[hh * 3 + 1], s1);
        s2 = fmaf(t, aw2[hh * 3 + 2], s2);
    }

    const float w0 = v0 + e0, w1 = v1 + e1, w2 = v2 + e2;

    float m0 = s0, m1 = s1, m2 = s2;
#pragma unroll
    for (int off = 1; off < 16; off <<= 1) {
        m0 = fmaxf(m0, __shfl_xor(m0, off));
        m1 = fmaxf(m1, __shfl_xor(m1, off));
        m2 = fmaxf(m2, __shfl_xor(m2, off));
    }
    const float ex0 = __expf(s0 - m0), ex1 = __expf(s1 - m1), ex2 = __expf(s2 - m2);
    float n0 = ex0 * w0, n1 = ex1 * w1, n2 = ex2 * w2;
    float den0 = ex0, den1 = ex1, den2 = ex2;
#pragma unroll
    for (int off = 1; off < 16; off <<= 1) {
        den0 += __shfl_xor(den0, off); n0 += __shfl_xor(n0, off);
        den1 += __shfl_xor(den1, off); n1 += __shfl_xor(n1, off);
        den2 += __shfl_xor(den2, off); n2 += __shfl_xor(n2, off);
    }

    if (j == 0) {
        const float h0 = 1.f / (1.f + __expf(-(n0 / den0)));
        const float h1 = 1.f / (1.f + __expf(-(n1 / den1)));
        const float h2 = 1.f / (1.f + __expf(-(n2 / den2)));
        if (!last) {
            hout[qg * 3 + 0] = h0;
            hout[qg * 3 + 1] = h1;
            hout[qg * 3 + 2] = h2;
        } else {
            const float o0 = fmaf(h0, lw[0], fmaf(h1, lw[2], fmaf(h2, lw[4], lb[0])));
            const float o1 = fmaf(h0, lw[1], fmaf(h1, lw[3], fmaf(h2, lw[5], lb[1])));
            const float mm = fmaxf(o0, o1);
            const float ea = __expf(o0 - mm), eb = __expf(o1 - mm);
            const float inv = 1.f / (ea + eb);
            out[qg * 2 + 0] = ea * inv;
            out[qg * 2 + 1] = eb * inv;
        }
    }
}

// ---------------- launch ----------------
extern "C" void kernel_launch(void* const* d_in, const int* in_sizes, int n_in,
                              void* d_out, int out_size, void* d_ws, size_t ws_size,
                              hipStream_t stream) {
    const float* feats = (const float*)d_in[0];
    const float* pos   = (const float*)d_in[1];
    const float* wqkv = (const float*)d_in[3];
    const float* pw1  = (const float*)d_in[4];
    const float* pb1  = (const float*)d_in[5];
    const float* pw2  = (const float*)d_in[6];
    const float* pb2  = (const float*)d_in[7];
    const float* aw1  = (const float*)d_in[8];
    const float* ab1  = (const float*)d_in[9];
    const float* aw2  = (const float*)d_in[10];
    const float* ab2  = (const float*)d_in[11];
    const float* lw   = (const float*)d_in[12];
    const float* lb   = (const float*)d_in[13];
    float* out = (float*)d_out;

    size_t o = 0;
    auto take = [&](size_t bytes) { size_t r = o; o += (bytes + 15) & ~(size_t)15; return r; };
    const size_t o_cnt   = take((size_t)(2 * MCELL + 4) * 4);  // cnt | cnt2 | ovf_cnt
    const size_t o_scan  = take((size_t)MCELL * 4);
    const size_t o_cs    = take((size_t)(MCELL + 1) * 4);
    const size_t o_bsum  = take((size_t)256 * 4);
    const size_t o_cid   = take((size_t)NQ * 4);
    const size_t o_spp   = take((size_t)NQ * 16);
    const size_t o_sidx  = take((size_t)NQ * 4);
    const size_t o_knn   = take((size_t)NQ * KNB * 4);
    const size_t o_ovfl  = take((size_t)NQ * 4);
    const size_t o_hA    = take((size_t)NQ * 3 * 4);
    const size_t o_hB    = take((size_t)NQ * 3 * 4);
    if (ws_size < o) return;

    char* ws = (char*)d_ws;
    int*    cnt     = (int*)(ws + o_cnt);
    int*    cnt2    = cnt + MCELL;
    int*    ovf_cnt = cnt + 2 * MCELL;
    int*    scan  = (int*)(ws + o_scan);
    int*    cs    = (int*)(ws + o_cs);
    int*    bsum  = (int*)(ws + o_bsum);
    int*    cid   = (int*)(ws + o_cid);
    float4* spp   = (float4*)(ws + o_spp);
    int*    sidx  = (int*)(ws + o_sidx);
    int*    knn   = (int*)(ws + o_knn);
    int*    ovfl  = (int*)(ws + o_ovfl);
    float*  hA    = (float*)(ws + o_hA);
    float*  hB    = (float*)(ws + o_hB);

    const int nscan = (MCELL + 1023) / 1024;

    kzero<<<(2 * MCELL + 1 + 255) / 256, 256, 0, stream>>>(cnt, 2 * MCELL + 1);
    kcount<<<NQ / 256, 256, 0, stream>>>(pos, cnt, cid);
    kscan1<<<nscan, 1024, 0, stream>>>(cnt, scan, bsum);
    kscan2<<<nscan, 1024, 0, stream>>>(scan, bsum, cs);
    kscatter<<<NQ / 256, 256, 0, stream>>>(pos, cid, cs, cnt2, spp, sidx);
    ksearch_fast<<<NQ / 4, 64, 0, stream>>>(spp, sidx, cs, knn, ovfl, ovf_cnt);
    ksearch_slow<<<SLOWG, 64, 0, stream>>>(spp, sidx, cs, knn, ovfl, ovf_cnt);

    pt_layer_f<<<NQ * 16 / 256, 256, 0, stream>>>(feats, pos, knn,
        wqkv + 0, pw1 + 0, pb1 + 0, pw2 + 0, pb2 + 0,
        aw1 + 0, ab1 + 0, aw2 + 0, ab2 + 0,
        hA, lw, lb, out, 0);
    pt_layer_f<<<NQ * 16 / 256, 256, 0, stream>>>(hA, pos, knn,
        wqkv + 27, pw1 + 96, pb1 + 32, pw2 + 96, pb2 + 3,
        aw1 + 36, ab1 + 12, aw2 + 36, ab2 + 3,
        hB, lw, lb, out, 0);
    pt_layer_f<<<NQ * 16 / 256, 256, 0, stream>>>(hB, pos, knn,
        wqkv + 54, pw1 + 192, pb1 + 64, pw2 + 192, pb2 + 6,
        aw1 + 72, ab1 + 24, aw2 + 72, ab2 + 6,
        hB, lw, lb, out, 1);
}

// Round 6
// 152.734 us; speedup vs baseline: 7.6548x; 1.2032x over previous
//
#include <hip/hip_runtime.h>
#include <math.h>

#define N_PTS 8192
#define BATCH 2
#define KNB 16
#define NQ (BATCH * N_PTS)          // 16384

// spatial grid
#define H    0.35f
#define INVH (1.0f / 0.35f)
#define NC   30
#define LBOX (0.5f * H * NC)        // 5.25
#define NCELL (NC * NC * NC)        // 27000
#define MCELL (2 * NCELL)           // 54000 (both batches)
#define RMAXF 2                     // fast-path max ring
#define SLOWG 1024                  // slow-path grid (blocks of 64)

typedef unsigned long long u64;

__device__ __forceinline__ float med3f(float a, float b, float c) {
#if __has_builtin(__builtin_amdgcn_fmed3f)
    return __builtin_amdgcn_fmed3f(a, b, c);
#else
    return fmaxf(fminf(a, b), fminf(fmaxf(a, b), c));
#endif
}

__device__ __forceinline__ unsigned sortable(float x) {
    unsigned u = __float_as_uint(x);
    return u ^ ((unsigned)((int)u >> 31) | 0x80000000u);
}

// ---------------- zero counters ----------------
__global__ __launch_bounds__(256) void kzero(int* __restrict__ p, int n) {
    const int i = blockIdx.x * 256 + threadIdx.x;
    if (i < n) p[i] = 0;
}

// ---------------- count points per cell ----------------
__global__ __launch_bounds__(256) void kcount(const float* __restrict__ pos,
                                              int* __restrict__ cnt,
                                              int* __restrict__ cellid) {
    const int g = blockIdx.x * 256 + threadIdx.x;
    const int b = g >> 13;
    const float x = pos[g * 3 + 0], y = pos[g * 3 + 1], z = pos[g * 3 + 2];
    int cx = (int)floorf((x + LBOX) * INVH); cx = min(max(cx, 0), NC - 1);
    int cy = (int)floorf((y + LBOX) * INVH); cy = min(max(cy, 0), NC - 1);
    int cz = (int)floorf((z + LBOX) * INVH); cz = min(max(cz, 0), NC - 1);
    const int c = (((b * NC) + cz) * NC + cy) * NC + cx;
    cellid[g] = c;
    atomicAdd(&cnt[c], 1);
}

// ---------------- prefix sum, level 1 ----------------
__global__ __launch_bounds__(1024) void kscan1(const int* __restrict__ cnt,
                                               int* __restrict__ scanned,
                                               int* __restrict__ bsum) {
    __shared__ int sh[1024];
    const int t = threadIdx.x;
    const int idx = blockIdx.x * 1024 + t;
    int v = (idx < MCELL) ? cnt[idx] : 0;
    sh[t] = v;
    __syncthreads();
    for (int off = 1; off < 1024; off <<= 1) {
        const int add = (t >= off) ? sh[t - off] : 0;
        __syncthreads();
        sh[t] += add;
        __syncthreads();
    }
    if (idx < MCELL) scanned[idx] = sh[t];
    if (t == 1023) bsum[blockIdx.x] = sh[1023];
}

// ---------------- prefix sum, level 2 ----------------
__global__ __launch_bounds__(1024) void kscan2(const int* __restrict__ scanned,
                                               const int* __restrict__ bsum,
                                               int* __restrict__ cell_start) {
    __shared__ int soff;
    const int t = threadIdx.x;
    const int blk = blockIdx.x;
    const int idx = blk * 1024 + t;
    if (t == 0) {
        int s = 0;
        for (int k = 0; k < blk; ++k) s += bsum[k];
        soff = s;
    }
    __syncthreads();
    if (idx < MCELL) cell_start[idx + 1] = scanned[idx] + soff;
    if (idx == 0) cell_start[0] = 0;
}

// ---------------- scatter points into cell-sorted order ----------------
__global__ __launch_bounds__(256) void kscatter(const float* __restrict__ pos,
                                                const int* __restrict__ cellid,
                                                const int* __restrict__ cell_start,
                                                int* __restrict__ cnt2,
                                                float4* __restrict__ spp,
                                                int* __restrict__ sidx) {
    const int g = blockIdx.x * 256 + threadIdx.x;
    const int c = cellid[g];
    const int off = atomicAdd(&cnt2[c], 1);
    const int p = cell_start[c] + off;
    const float x = pos[g * 3 + 0], y = pos[g * 3 + 1], z = pos[g * 3 + 2];
    spp[p] = make_float4(-2.f * x, -2.f * y, -2.f * z, fmaf(x, x, fmaf(y, y, z * z)));
    sidx[p] = g & (N_PTS - 1);
}

// ---------------- fast kNN: 16 lanes/query, rings R<=2, else overflow ----------------
__global__ __launch_bounds__(64) void ksearch_fast(const float4* __restrict__ spp,
                                                   const int* __restrict__ sidx,
                                                   const int* __restrict__ cs,
                                                   int* __restrict__ knn,
                                                   int* __restrict__ ovf_list,
                                                   int* __restrict__ ovf_cnt) {
    const int tid = threadIdx.x;
    const int li  = tid & 15;
    const int sq  = blockIdx.x * 4 + (tid >> 4);
    const int b   = sq >> 13;

    const float4 me = spp[sq];
    const float qx = -0.5f * me.x, qy = -0.5f * me.y, qz = -0.5f * me.z;
    const float qsq = me.w;
    int cx = (int)floorf((qx + LBOX) * INVH); cx = min(max(cx, 0), NC - 1);
    int cy = (int)floorf((qy + LBOX) * INVH); cy = min(max(cy, 0), NC - 1);
    int cz = (int)floorf((qz + LBOX) * INVH); cz = min(max(cz, 0), NC - 1);

    auto do_ring = [&](int R, auto&& body) {
        const int zlo = max(cz - R, 0), zhi = min(cz + R, NC - 1);
        const int ylo = max(cy - R, 0), yhi = min(cy + R, NC - 1);
        const int xlo = max(cx - R, 0), xhi = min(cx + R, NC - 1);
        for (int z = zlo; z <= zhi; ++z) {
            const bool zf = (z == cz - R) || (z == cz + R);
            for (int y = ylo; y <= yhi; ++y) {
                const bool face = zf || (y == cy - R) || (y == cy + R);
                const int rowb = (((b * NC) + z) * NC + y) * NC;
                if (face) {
                    const int st = cs[rowb + xlo], en = cs[rowb + xhi + 1];
                    for (int p = st + li; p < en; p += 16) body(p);
                } else {
                    const int xm = cx - R, xp = cx + R;
                    if (xm >= 0) {
                        const int st = cs[rowb + xm], en = cs[rowb + xm + 1];
                        for (int p = st + li; p < en; p += 16) body(p);
                    }
                    if (xp < NC) {
                        const int st = cs[rowb + xp], en = cs[rowb + xp + 1];
                        for (int p = st + li; p < en; p += 16) body(p);
                    }
                }
            }
        }
    };

    // ---- pass 1: per-lane top-16 float keys (guarded med3 chain) ----
    float d[KNB];
#pragma unroll
    for (int k = 0; k < KNB; ++k) d[k] = 3.4e38f;

    auto scan1 = [&](int p) {
        const float4 v = spp[p];
        const float x = fmaf(qx, v.x, fmaf(qy, v.y, fmaf(qz, v.z, v.w)));
        if (x < d[0]) {
#pragma unroll
            for (int s = 0; s < KNB - 1; ++s) d[s] = med3f(d[s], d[s + 1], x);
            d[KNB - 1] = fminf(d[KNB - 1], x);
        }
    };

    int Rfin = -1;
    for (int R = 0; R <= RMAXF; ++R) {
        do_ring(R, scan1);
        const float bxl = fmaf((float)(cx - R), H, -LBOX);
        const float bxh = fmaf((float)(cx + R + 1), H, -LBOX);
        const float byl = fmaf((float)(cy - R), H, -LBOX);
        const float byh = fmaf((float)(cy + R + 1), H, -LBOX);
        const float bzl = fmaf((float)(cz - R), H, -LBOX);
        const float bzh = fmaf((float)(cz + R + 1), H, -LBOX);
        const float m = fminf(fminf(fminf(qx - bxl, bxh - qx),
                                    fminf(qy - byl, byh - qy)),
                              fminf(qz - bzl, bzh - qz));
        if (m > 0.f) {
            const float Bf = fmaf(m, m, -1e-4f) - qsq;
            int c = 0;
#pragma unroll
            for (int k = 0; k < KNB; ++k) c += (d[k] <= Bf) ? 1 : 0;
#pragma unroll
            for (int off = 1; off < 16; off <<= 1) c += __shfl_xor(c, off);
            if (c >= KNB) { Rfin = R; break; }
        }
    }

    if (Rfin < 0) {
        if (li == 0) { const int s2 = atomicAdd(ovf_cnt, 1); ovf_list[s2] = sq; }
        return;
    }

    // ---- merge per-lane float tops -> global top-16 keys (all lanes) ----
#pragma unroll
    for (int mm = 1; mm <= 8; mm <<= 1) {
        float L[KNB];
#pragma unroll
        for (int i = 0; i < KNB; ++i)
            L[i] = fminf(d[i], __shfl_xor(d[KNB - 1 - i], mm));
#pragma unroll
        for (int dd = 8; dd >= 1; dd >>= 1) {
#pragma unroll
            for (int i = 0; i < KNB; ++i) {
                if ((i & dd) == 0) {
                    const float hi = fmaxf(L[i], L[i | dd]);
                    const float lo = fminf(L[i], L[i | dd]);
                    L[i] = hi; L[i | dd] = lo;
                }
            }
        }
#pragma unroll
        for (int i = 0; i < KNB; ++i) d[i] = L[i];
    }
    const float thr = d[0];           // exact global 16th-smallest key

    // ---- pass 2 (cache-hot): exact (key,idx) top-16 among x <= thr ----
    u64 pk[KNB];
#pragma unroll
    for (int k = 0; k < KNB; ++k) pk[k] = 0xFFFFFFFFFFFFFFFFull;

    auto scan2 = [&](int p) {
        const float4 v = spp[p];
        const float x = fmaf(qx, v.x, fmaf(qy, v.y, fmaf(qz, v.z, v.w)));
        if (x <= thr) {
            const u64 key = ((u64)sortable(x) << 32) | (unsigned)sidx[p];
            if (key < pk[0]) {
#pragma unroll
                for (int s = 0; s < KNB; ++s) {
                    const u64 ds1 = (s < KNB - 1) ? pk[s + 1] : 0ull;
                    const bool c0 = key < pk[s];
                    const bool c1 = key < ds1;
                    pk[s] = c1 ? ds1 : (c0 ? key : pk[s]);
                }
            }
        }
    };
    for (int R = 0; R <= Rfin; ++R) do_ring(R, scan2);

    // ---- u64 16-lane bitonic merge -> exact global top-16 (key,idx) ----
#pragma unroll
    for (int mm = 1; mm <= 8; mm <<= 1) {
        u64 L[KNB];
#pragma unroll
        for (int i = 0; i < KNB; ++i) {
            const u64 a = pk[i];
            const u64 c = __shfl_xor(pk[KNB - 1 - i], mm);
            L[i] = a < c ? a : c;
        }
#pragma unroll
        for (int dd = 8; dd >= 1; dd >>= 1) {
#pragma unroll
            for (int i = 0; i < KNB; ++i) {
                if ((i & dd) == 0) {
                    const u64 hi = L[i] > L[i | dd] ? L[i] : L[i | dd];
                    const u64 lo = L[i] > L[i | dd] ? L[i | dd] : L[i];
                    L[i] = hi; L[i | dd] = lo;
                }
            }
        }
#pragma unroll
        for (int i = 0; i < KNB; ++i) pk[i] = L[i];
    }

    const int qorig = sidx[sq];
    const int obase = ((b << 13) + qorig) * KNB;
    u64 sel = pk[0];
#pragma unroll
    for (int s = 1; s < KNB; ++s) sel = (li == s) ? pk[s] : sel;
    knn[obase + li] = (int)(unsigned)(sel & 0xFFFFFFFFull);
}

// ---------------- slow kNN: brute-force full batch scan, one wave per overflow query ----------------
// Overflow queries live in the sparse Gaussian shell; ring-walking them is a
// latency chain over empty cells. A regular 8192-point scan (128 coalesced
// float4 loads/lane, L2-resident) with guarded u64 insert is exact and fast.
__global__ __launch_bounds__(64) void ksearch_slow(const float4* __restrict__ spp,
                                                   const int* __restrict__ sidx,
                                                   int* __restrict__ knn,
                                                   const int* __restrict__ ovf_list,
                                                   const int* __restrict__ ovf_cnt) {
    const int lane = threadIdx.x;
    const int nov = *ovf_cnt;

    for (int w = blockIdx.x; w < nov; w += SLOWG) {
        const int sq = ovf_list[w];
        const int b  = sq >> 13;
        const float4 me = spp[sq];
        const float qx = -0.5f * me.x, qy = -0.5f * me.y, qz = -0.5f * me.z;
        const int base = b << 13;

        u64 pk[KNB];
#pragma unroll
        for (int k = 0; k < KNB; ++k) pk[k] = 0xFFFFFFFFFFFFFFFFull;

#pragma unroll 4
        for (int t = lane; t < N_PTS; t += 64) {
            const float4 v = spp[base + t];
            const float x = fmaf(qx, v.x, fmaf(qy, v.y, fmaf(qz, v.z, v.w)));
            const u64 key = ((u64)sortable(x) << 32) | (unsigned)sidx[base + t];
            if (key < pk[0]) {
#pragma unroll
                for (int s = 0; s < KNB; ++s) {
                    const u64 ds1 = (s < KNB - 1) ? pk[s + 1] : 0ull;
                    const bool c0 = key < pk[s];
                    const bool c1 = key < ds1;
                    pk[s] = c1 ? ds1 : (c0 ? key : pk[s]);
                }
            }
        }

        // 64-lane bitonic merge (6 rounds)
#pragma unroll
        for (int mm = 1; mm <= 32; mm <<= 1) {
            u64 L[KNB];
#pragma unroll
            for (int i = 0; i < KNB; ++i) {
                const u64 a = pk[i];
                const u64 c = __shfl_xor(pk[KNB - 1 - i], mm);
                L[i] = a < c ? a : c;
            }
#pragma unroll
            for (int dd = 8; dd >= 1; dd >>= 1) {
#pragma unroll
                for (int i = 0; i < KNB; ++i) {
                    if ((i & dd) == 0) {
                        const u64 hi = L[i] > L[i | dd] ? L[i] : L[i | dd];
                        const u64 lo = L[i] > L[i | dd] ? L[i | dd] : L[i];
                        L[i] = hi; L[i | dd] = lo;
                    }
                }
            }
#pragma unroll
            for (int i = 0; i < KNB; ++i) pk[i] = L[i];
        }

        const int qorig = sidx[sq];
        const int obase = ((b << 13) + qorig) * KNB;
        u64 sel = pk[0];
#pragma unroll
        for (int s = 1; s < KNB; ++s) sel = (lane == s) ? pk[s] : sel;
        if (lane < KNB) knn[obase + lane] = (int)(unsigned)(sel & 0xFFFFFFFFull);
    }
}

// ---------------- fused PT layer: per-edge MLPs + 16-lane shuffle softmax ----------------
__global__ __launch_bounds__(256) void pt_layer_f(const float* __restrict__ hin,
                                                  const float* __restrict__ pos,
                                                  const int* __restrict__ knn,
                                                  const float* __restrict__ wqkv,
                                                  const float* __restrict__ pw1,
                                                  const float* __restrict__ pb1,
                                                  const float* __restrict__ pw2,
                                                  const float* __restrict__ pb2,
                                                  const float* __restrict__ aw1,
                                                  const float* __restrict__ ab1,
                                                  const float* __restrict__ aw2,
                                                  const float* __restrict__ ab2,
                                                  float* __restrict__ hout,
                                                  const float* __restrict__ lw,
                                                  const float* __restrict__ lb,
                                                  float* __restrict__ out,
                                                  int last) {
    const int gt = blockIdx.x * 256 + threadIdx.x;
    const int qg = gt >> 4;
    const int j  = gt & 15;
    const int b  = qg >> 13;
    const int jj = knn[qg * KNB + j] & (N_PTS - 1);
    const int g  = (b << 13) + jj;

    const float hi0 = hin[qg * 3 + 0], hi1 = hin[qg * 3 + 1], hi2 = hin[qg * 3 + 2];
    const float hj0 = hin[g * 3 + 0],  hj1 = hin[g * 3 + 1],  hj2 = hin[g * 3 + 2];
    const float rx = pos[qg * 3 + 0] - pos[g * 3 + 0];
    const float ry = pos[qg * 3 + 1] - pos[g * 3 + 1];
    const float rz = pos[qg * 3 + 2] - pos[g * 3 + 2];

    const float q0 = fmaf(hi0, wqkv[0], fmaf(hi1, wqkv[9],  hi2 * wqkv[18]));
    const float q1 = fmaf(hi0, wqkv[1], fmaf(hi1, wqkv[10], hi2 * wqkv[19]));
    const float q2 = fmaf(hi0, wqkv[2], fmaf(hi1, wqkv[11], hi2 * wqkv[20]));
    const float k0 = fmaf(hj0, wqkv[3], fmaf(hj1, wqkv[12], hj2 * wqkv[21]));
    const float k1 = fmaf(hj0, wqkv[4], fmaf(hj1, wqkv[13], hj2 * wqkv[22]));
    const float k2 = fmaf(hj0, wqkv[5], fmaf(hj1, wqkv[14], hj2 * wqkv[23]));
    const float v0 = fmaf(hj0, wqkv[6], fmaf(hj1, wqkv[15], hj2 * wqkv[24]));
    const float v1 = fmaf(hj0, wqkv[7], fmaf(hj1, wqkv[16], hj2 * wqkv[25]));
    const float v2 = fmaf(hj0, wqkv[8], fmaf(hj1, wqkv[17], hj2 * wqkv[26]));

    float e0 = pb2[0], e1 = pb2[1], e2 = pb2[2];
#pragma unroll
    for (int hh = 0; hh < 32; ++hh) {
        float t = fmaf(rx, pw1[hh], fmaf(ry, pw1[32 + hh], fmaf(rz, pw1[64 + hh], pb1[hh])));
        t = fmaxf(t, 0.0f);
        e0 = fmaf(t, pw2[hh * 3 + 0], e0);
        e1 = fmaf(t, pw2[hh * 3 + 1], e1);
        e2 = fmaf(t, pw2[hh * 3 + 2], e2);
    }

    const float x0 = q0 - k0 + e0;
    const float x1 = q1 - k1 + e1;
    const float x2 = q2 - k2 + e2;

    float s0 = ab2[0], s1 = ab2[1], s2 = ab2[2];
#pragma unroll
    for (int hh = 0; hh < 12; ++hh) {
        float t = fmaf(x0, aw1[hh], fmaf(x1, aw1[12 + hh], fmaf(x2, aw1[24 + hh], ab1[hh])));
        t = fmaxf(t, 0.0f);
        s0 = fmaf(t, aw2[hh * 3 + 0], s0);
        s1 = fmaf(t, aw2[hh * 3 + 1], s1);
        s2 = fmaf(t, aw2[hh * 3 + 2], s2);
    }

    const float w0 = v0 + e0, w1 = v1 + e1, w2 = v2 + e2;

    float m0 = s0, m1 = s1, m2 = s2;
#pragma unroll
    for (int off = 1; off < 16; off <<= 1) {
        m0 = fmaxf(m0, __shfl_xor(m0, off));
        m1 = fmaxf(m1, __shfl_xor(m1, off));
        m2 = fmaxf(m2, __shfl_xor(m2, off));
    }
    const float ex0 = __expf(s0 - m0), ex1 = __expf(s1 - m1), ex2 = __expf(s2 - m2);
    float n0 = ex0 * w0, n1 = ex1 * w1, n2 = ex2 * w2;
    float den0 = ex0, den1 = ex1, den2 = ex2;
#pragma unroll
    for (int off = 1; off < 16; off <<= 1) {
        den0 += __shfl_xor(den0, off); n0 += __shfl_xor(n0, off);
        den1 += __shfl_xor(den1, off); n1 += __shfl_xor(n1, off);
        den2 += __shfl_xor(den2, off); n2 += __shfl_xor(n2, off);
    }

    if (j == 0) {
        const float h0 = 1.f / (1.f + __expf(-(n0 / den0)));
        const float h1 = 1.f / (1.f + __expf(-(n1 / den1)));
        const float h2 = 1.f / (1.f + __expf(-(n2 / den2)));
        if (!last) {
            hout[qg * 3 + 0] = h0;
            hout[qg * 3 + 1] = h1;
            hout[qg * 3 + 2] = h2;
        } else {
            const float o0 = fmaf(h0, lw[0], fmaf(h1, lw[2], fmaf(h2, lw[4], lb[0])));
            const float o1 = fmaf(h0, lw[1], fmaf(h1, lw[3], fmaf(h2, lw[5], lb[1])));
            const float mm = fmaxf(o0, o1);
            const float ea = __expf(o0 - mm), eb = __expf(o1 - mm);
            const float inv = 1.f / (ea + eb);
            out[qg * 2 + 0] = ea * inv;
            out[qg * 2 + 1] = eb * inv;
        }
    }
}

// ---------------- launch ----------------
extern "C" void kernel_launch(void* const* d_in, const int* in_sizes, int n_in,
                              void* d_out, int out_size, void* d_ws, size_t ws_size,
                              hipStream_t stream) {
    const float* feats = (const float*)d_in[0];
    const float* pos   = (const float*)d_in[1];
    const float* wqkv = (const float*)d_in[3];
    const float* pw1  = (const float*)d_in[4];
    const float* pb1  = (const float*)d_in[5];
    const float* pw2  = (const float*)d_in[6];
    const float* pb2  = (const float*)d_in[7];
    const float* aw1  = (const float*)d_in[8];
    const float* ab1  = (const float*)d_in[9];
    const float* aw2  = (const float*)d_in[10];
    const float* ab2  = (const float*)d_in[11];
    const float* lw   = (const float*)d_in[12];
    const float* lb   = (const float*)d_in[13];
    float* out = (float*)d_out;

    size_t o = 0;
    auto take = [&](size_t bytes) { size_t r = o; o += (bytes + 15) & ~(size_t)15; return r; };
    const size_t o_cnt   = take((size_t)(2 * MCELL + 4) * 4);  // cnt | cnt2 | ovf_cnt
    const size_t o_scan  = take((size_t)MCELL * 4);
    const size_t o_cs    = take((size_t)(MCELL + 1) * 4);
    const size_t o_bsum  = take((size_t)256 * 4);
    const size_t o_cid   = take((size_t)NQ * 4);
    const size_t o_spp   = take((size_t)NQ * 16);
    const size_t o_sidx  = take((size_t)NQ * 4);
    const size_t o_knn   = take((size_t)NQ * KNB * 4);
    const size_t o_ovfl  = take((size_t)NQ * 4);
    const size_t o_hA    = take((size_t)NQ * 3 * 4);
    const size_t o_hB    = take((size_t)NQ * 3 * 4);
    if (ws_size < o) return;

    char* ws = (char*)d_ws;
    int*    cnt     = (int*)(ws + o_cnt);
    int*    cnt2    = cnt + MCELL;
    int*    ovf_cnt = cnt + 2 * MCELL;
    int*    scan  = (int*)(ws + o_scan);
    int*    cs    = (int*)(ws + o_cs);
    int*    bsum  = (int*)(ws + o_bsum);
    int*    cid   = (int*)(ws + o_cid);
    float4* spp   = (float4*)(ws + o_spp);
    int*    sidx  = (int*)(ws + o_sidx);
    int*    knn   = (int*)(ws + o_knn);
    int*    ovfl  = (int*)(ws + o_ovfl);
    float*  hA    = (float*)(ws + o_hA);
    float*  hB    = (float*)(ws + o_hB);

    const int nscan = (MCELL + 1023) / 1024;

    kzero<<<(2 * MCELL + 1 + 255) / 256, 256, 0, stream>>>(cnt, 2 * MCELL + 1);
    kcount<<<NQ / 256, 256, 0, stream>>>(pos, cnt, cid);
    kscan1<<<nscan, 1024, 0, stream>>>(cnt, scan, bsum);
    kscan2<<<nscan, 1024, 0, stream>>>(scan, bsum, cs);
    kscatter<<<NQ / 256, 256, 0, stream>>>(pos, cid, cs, cnt2, spp, sidx);
    ksearch_fast<<<NQ / 4, 64, 0, stream>>>(spp, sidx, cs, knn, ovfl, ovf_cnt);
    ksearch_slow<<<SLOWG, 64, 0, stream>>>(spp, sidx, knn, ovfl, ovf_cnt);

    pt_layer_f<<<NQ * 16 / 256, 256, 0, stream>>>(feats, pos, knn,
        wqkv + 0, pw1 + 0, pb1 + 0, pw2 + 0, pb2 + 0,
        aw1 + 0, ab1 + 0, aw2 + 0, ab2 + 0,
        hA, lw, lb, out, 0);
    pt_layer_f<<<NQ * 16 / 256, 256, 0, stream>>>(hA, pos, knn,
        wqkv + 27, pw1 + 96, pb1 + 32, pw2 + 96, pb2 + 3,
        aw1 + 36, ab1 + 12, aw2 + 36, ab2 + 3,
        hB, lw, lb, out, 0);
    pt_layer_f<<<NQ * 16 / 256, 256, 0, stream>>>(hB, pos, knn,
        wqkv + 54, pw1 + 192, pb1 + 64, pw2 + 192, pb2 + 6,
        aw1 + 72, ab1 + 24, aw2 + 72, ab2 + 6,
        hB, lw, lb, out, 1);
}